// Round 3
// baseline (168.603 us; speedup 1.0000x reference)
//
#include <hip/hip_runtime.h>
#include <math.h>

#define NB 32
#define NT 512
#define NS 64
#define NOBS 4
#define NEMB 32
#define NPE 16
#define NATTN 10
#define ND 26  // ATTN + PE

typedef _Float16 half4_t __attribute__((ext_vector_type(4)));
typedef _Float16 half8_t __attribute__((ext_vector_type(8)));
typedef float float4_t __attribute__((ext_vector_type(4)));

// obs_emb_weights LDS layout: 64 rows (sensor s) x 128 dwords (o*32+e),
// 16B-chunk XOR swizzle so per-lane ds_read_b128 of row s spreads banks.
__device__ __forceinline__ int obs_idx(int s, int chunk) {
    return (s << 7) + (((chunk ^ (s & 7)) & 31) << 2);
}

__global__ __launch_bounds__(512)
void raindrop_kernel(const float* __restrict__ x,
                     const float* __restrict__ times,
                     const float* __restrict__ mask,
                     const float* __restrict__ obsW,
                     const float* __restrict__ attnW,
                     const float* __restrict__ recvW,
                     const float* __restrict__ recvB,
                     float* __restrict__ out)
{
    // 32 KiB: phase 1 = swizzled obsW tile; phase 3 = per-wave A rows (2KB each)
    __shared__ float lds[NS * 128];
    // 2 KiB: B^T, u-major: Btr[u][k], k 0..9 = attnW[u], k10 = 1.0, k11..15 = 0
    __shared__ _Float16 Btr[NS * 16];

    const int tid = threadIdx.x;

    // Stage S*OBS*EMB = 8192 floats into LDS (coalesced global float4 reads,
    // swizzled LDS writes). 512 threads x 4 iters x 4 floats.
#pragma unroll
    for (int k = 0; k < 4; ++k) {
        int i = (tid << 2) + (k << 11);
        float4 v = *reinterpret_cast<const float4*>(obsW + i);
        int si = i >> 7;
        int c = (i & 127) >> 2;
        *reinterpret_cast<float4*>(&lds[obs_idx(si, c)]) = v;
    }

    // Build Btr once per block (threads 0..63, one u each; tiny, L2-hit reads)
    if (tid < NS) {
        const float* ar = attnW + tid * NATTN;
        half8_t lo, hi;
#pragma unroll
        for (int q = 0; q < 8; ++q) lo[q] = (_Float16)ar[q];
        hi[0] = (_Float16)ar[8];
        hi[1] = (_Float16)ar[9];
        hi[2] = (_Float16)1.0f;   // beta slot
        hi[3] = hi[4] = hi[5] = hi[6] = hi[7] = (_Float16)0.0f;  // k pad MUST be 0
        *reinterpret_cast<half8_t*>(&Btr[tid * 16])     = lo;
        *reinterpret_cast<half8_t*>(&Btr[tid * 16 + 8]) = hi;
    }

    const int lane = tid & 63;
    const int wv = tid >> 6;
    const int bt = blockIdx.x * 8 + wv;   // one wave per (b,t)
    const int s = lane;                   // phase-1 role: lane = sensor

    // positional encoding (wave-uniform; div[i] = 10^(-i/2)); native sin/cos
    const float tt = times[bt];
    const float divs[8] = {1.0f, 0.31622776601683794f, 0.1f, 0.031622776601683794f,
                           0.01f, 0.0031622776601683794f, 0.001f, 0.00031622776601683794f};
    float pe[NPE];
#pragma unroll
    for (int i = 0; i < 8; ++i) {
        float ang = tt * divs[i];
        pe[2 * i]     = __sinf(ang);
        pe[2 * i + 1] = __cosf(ang);
    }

    // per-lane inputs (coalesced: 64 lanes x 16B contiguous)
    const float4 xv = *reinterpret_cast<const float4*>(x + ((size_t)bt * NS + s) * NOBS);
    const float  mv = mask[(size_t)bt * NS + s];

    __syncthreads();  // obsW tile + Btr ready

    // hq[d] = recv_b[d] + sum_e h_e * recv_W[e][d],
    // h_e = relu(sum_o x_o * obsW[s][o][e]) * mask
    float hq[ND];
#pragma unroll
    for (int d = 0; d < ND; ++d) hq[d] = recvB[d];  // uniform -> s_load

#pragma unroll
    for (int eb = 0; eb < 8; ++eb) {  // e = eb*4 + j
        float a0 = 0.f, a1 = 0.f, a2 = 0.f, a3 = 0.f;
        {
            float4 w0 = *reinterpret_cast<const float4*>(&lds[obs_idx(s, 0 * 8 + eb)]);
            a0 += xv.x * w0.x; a1 += xv.x * w0.y; a2 += xv.x * w0.z; a3 += xv.x * w0.w;
            float4 w1 = *reinterpret_cast<const float4*>(&lds[obs_idx(s, 1 * 8 + eb)]);
            a0 += xv.y * w1.x; a1 += xv.y * w1.y; a2 += xv.y * w1.z; a3 += xv.y * w1.w;
            float4 w2 = *reinterpret_cast<const float4*>(&lds[obs_idx(s, 2 * 8 + eb)]);
            a0 += xv.z * w2.x; a1 += xv.z * w2.y; a2 += xv.z * w2.z; a3 += xv.z * w2.w;
            float4 w3 = *reinterpret_cast<const float4*>(&lds[obs_idx(s, 3 * 8 + eb)]);
            a0 += xv.w * w3.x; a1 += xv.w * w3.y; a2 += xv.w * w3.z; a3 += xv.w * w3.w;
        }
        const float h0 = fmaxf(a0, 0.f) * mv;
        const float h1 = fmaxf(a1, 0.f) * mv;
        const float h2 = fmaxf(a2, 0.f) * mv;
        const float h3 = fmaxf(a3, 0.f) * mv;
        const float* rw = recvW + (eb * 4) * ND;  // uniform base -> s_load
#pragma unroll
        for (int d = 0; d < ND; ++d) {
            hq[d] += h0 * rw[d] + h1 * rw[ND + d] + h2 * rw[2 * ND + d] + h3 * rw[3 * ND + d];
        }
    }

    // u-independent part: beta_s = recv-PE dot (recv_b folded via hq init)
    float beta = 0.f;
#pragma unroll
    for (int p = 0; p < NPE; ++p) beta += hq[NATTN + p] * pe[p];

    __syncthreads();  // all waves done READING the obsW tile -> safe to reuse

    // A rows (per-wave 2KB region of the reused lds): A[r][k] f16, 16 k per row.
    // k 0..9 = hq, k10 = beta, k11..15 = 0 (pad MUST be 0: garbage could be NaN
    // and NaN*0 would poison the accumulator even though B's pads are zero).
    _Float16* Ab = reinterpret_cast<_Float16*>(&lds[wv * 512]);
    {
        half8_t lo, hi;
#pragma unroll
        for (int q = 0; q < 8; ++q) lo[q] = (_Float16)hq[q];
        hi[0] = (_Float16)hq[8];
        hi[1] = (_Float16)hq[9];
        hi[2] = (_Float16)beta;
        hi[3] = hi[4] = hi[5] = hi[6] = hi[7] = (_Float16)0.0f;
        *reinterpret_cast<half8_t*>(Ab + s * 16)     = lo;
        *reinterpret_cast<half8_t*>(Ab + s * 16 + 8) = hi;
    }

    __syncthreads();  // A rows visible (cheap insurance over wave-order LDS)

    // Phase 3: 64x64 = 16 x mfma_f32_16x16x16_f16.
    // A-frag: lane holds A[m = lane&15][k = (lane>>4)*4 + i], i=0..3
    // B-frag: lane holds B[k = (lane>>4)*4 + i][n = lane&15]  (= Btr[n][k])
    // C: col = lane&15, row = (lane>>4)*4 + reg  (m89-verified 16x16 layout)
    const int lm = lane & 15;
    const int lkh = (lane >> 4) * 4;

    half4_t bfrag[4];
#pragma unroll
    for (int ni = 0; ni < 4; ++ni)
        bfrag[ni] = *reinterpret_cast<const half4_t*>(&Btr[(ni * 16 + lm) * 16 + lkh]);

    float* obase = out + (size_t)bt * (NS * NS);
#pragma unroll
    for (int mi = 0; mi < 4; ++mi) {
        half4_t af = *reinterpret_cast<const half4_t*>(Ab + (mi * 16 + lm) * 16 + lkh);
        float4_t c0 = {0.f, 0.f, 0.f, 0.f};
        float4_t c1 = {0.f, 0.f, 0.f, 0.f};
        float4_t c2 = {0.f, 0.f, 0.f, 0.f};
        float4_t c3 = {0.f, 0.f, 0.f, 0.f};
        c0 = __builtin_amdgcn_mfma_f32_16x16x16f16(af, bfrag[0], c0, 0, 0, 0);
        c1 = __builtin_amdgcn_mfma_f32_16x16x16f16(af, bfrag[1], c1, 0, 0, 0);
        c2 = __builtin_amdgcn_mfma_f32_16x16x16f16(af, bfrag[2], c2, 0, 0, 0);
        c3 = __builtin_amdgcn_mfma_f32_16x16x16f16(af, bfrag[3], c3, 0, 0, 0);
        // rows r = mi*16 + (lane>>4)*4 + i, cols ni*16 + lm.
        // Each store: 4 x 16 lanes x 4B = four fully-covered 64B lines.
        float* orow = obase + (size_t)(mi * 16 + (lane >> 4) * 4) * NS + lm;
#pragma unroll
        for (int i = 0; i < 4; ++i) {
            orow[i * NS +  0] = fmaxf(c0[i], 0.f);
            orow[i * NS + 16] = fmaxf(c1[i], 0.f);
            orow[i * NS + 32] = fmaxf(c2[i], 0.f);
            orow[i * NS + 48] = fmaxf(c3[i], 0.f);
        }
    }
}

extern "C" void kernel_launch(void* const* d_in, const int* in_sizes, int n_in,
                              void* d_out, int out_size, void* d_ws, size_t ws_size,
                              hipStream_t stream) {
    const float* x     = (const float*)d_in[0];
    const float* times = (const float*)d_in[1];
    const float* mask  = (const float*)d_in[2];
    const float* obsW  = (const float*)d_in[3];
    const float* attnW = (const float*)d_in[4];
    const float* recvW = (const float*)d_in[5];
    const float* recvB = (const float*)d_in[6];
    float* out = (float*)d_out;

    // B*T = 16384 (b,t) pairs, one wave each, 8 waves per block
    raindrop_kernel<<<dim3((NB * NT) / 8), dim3(512), 0, stream>>>(
        x, times, mask, obsW, attnW, recvW, recvB, out);
}